// Round 5
// baseline (278.618 us; speedup 1.0000x reference)
//
#include <hip/hip_runtime.h>

#define N_NODES 50000
#define EPS 1e-6f
#define SCAN_BLOCKS 196   // 196*256 = 50176 >= N_NODES

// ---------------- Workspace layout ----------------
// cnt    : 50176 ints  (zeroed each call)
// off    : 50176 ints  (off[N] = E total)
// cursor : 50176 ints
// bsum   : 256 ints
// ssrc   : E ints      (src ids grouped by dst)
// mean1  : N*64 floats
// g      : N*64 floats (relu(mean1@W1+b1) @ W2, pre-gather)
//
// NUMERICS CONTRACT (round-4 post-mortem): all float accumulation orders are
// bit-identical to the round-3 kernel that measured absmax 0.03125:
//  - gather neighbor sums: global groups-of-4 with (v0+v1)+(v2+v3), tail sequential
//  - log-softmax: butterfly over feature bits 5..0, epilogue (val-mx)-logf(sm)
// Integer paths (hist/fill/scan) may be restructured freely (exact sums).

// ---- CSR build ----
__global__ __launch_bounds__(256) void hist_kernel(
    const int* __restrict__ dst, int* __restrict__ cnt, int E) {
  int i = blockIdx.x * 256 + threadIdx.x;
  int n4 = E >> 2;
  if (i < n4) {
    int4 d = ((const int4*)dst)[i];
    atomicAdd(&cnt[d.x], 1);
    atomicAdd(&cnt[d.y], 1);
    atomicAdd(&cnt[d.z], 1);
    atomicAdd(&cnt[d.w], 1);
  } else if (i < n4 + (E & 3)) {
    atomicAdd(&cnt[dst[4 * n4 + (i - n4)]], 1);
  }
}

__global__ __launch_bounds__(256) void scan1_kernel(
    const int* __restrict__ cnt, int* __restrict__ bsum) {
  __shared__ int red[4];
  int t = threadIdx.x;
  int i = blockIdx.x * 256 + t;
  int v = (i < N_NODES) ? cnt[i] : 0;
#pragma unroll
  for (int o = 32; o > 0; o >>= 1) v += __shfl_xor(v, o, 64);
  if ((t & 63) == 0) red[t >> 6] = v;
  __syncthreads();
  if (t == 0) bsum[blockIdx.x] = red[0] + red[1] + red[2] + red[3];
}

__global__ __launch_bounds__(256) void scan2_kernel(
    int* __restrict__ bsum, int* __restrict__ off) {
  __shared__ int wsum[4];
  int t = threadIdx.x;
  int v = (t < SCAN_BLOCKS) ? bsum[t] : 0;
  int lane = t & 63, wv = t >> 6;
  int x = v;
#pragma unroll
  for (int d = 1; d < 64; d <<= 1) {
    int y = __shfl_up(x, d, 64);
    if (lane >= d) x += y;
  }
  if (lane == 63) wsum[wv] = x;
  __syncthreads();
  int add = 0;
  for (int w = 0; w < wv; w++) add += wsum[w];
  x += add;
  if (t < SCAN_BLOCKS) bsum[t] = x - v;
  if (t == SCAN_BLOCKS - 1) off[N_NODES] = x;
}

__global__ __launch_bounds__(256) void scan3_kernel(
    const int* __restrict__ cnt, const int* __restrict__ bsum,
    int* __restrict__ off, int* __restrict__ cursor) {
  __shared__ int wsum[4];
  int t = threadIdx.x;
  int i = blockIdx.x * 256 + t;
  int v = (i < N_NODES) ? cnt[i] : 0;
  int lane = t & 63, wv = t >> 6;
  int x = v;
#pragma unroll
  for (int d = 1; d < 64; d <<= 1) {
    int y = __shfl_up(x, d, 64);
    if (lane >= d) x += y;
  }
  if (lane == 63) wsum[wv] = x;
  __syncthreads();
  int add = bsum[blockIdx.x];
  for (int w = 0; w < wv; w++) add += wsum[w];
  int excl = add + x - v;
  if (i < N_NODES) {
    off[i] = excl;
    cursor[i] = excl;
  }
}

// 4 edges/thread: 4 independent atomic chains in flight (bin ORDER changes vs
// round 3 but rounds 1-3 showed summation order does not move absmax)
__global__ __launch_bounds__(256) void fill_kernel(
    const int* __restrict__ src, const int* __restrict__ dst,
    int* __restrict__ cursor, int* __restrict__ ssrc, int E) {
  int i = blockIdx.x * 256 + threadIdx.x;
  int n4 = E >> 2;
  if (i < n4) {
    int4 d = ((const int4*)dst)[i];
    int4 s = ((const int4*)src)[i];
    int p0 = atomicAdd(&cursor[d.x], 1);
    int p1 = atomicAdd(&cursor[d.y], 1);
    int p2 = atomicAdd(&cursor[d.z], 1);
    int p3 = atomicAdd(&cursor[d.w], 1);
    ssrc[p0] = s.x;
    ssrc[p1] = s.y;
    ssrc[p2] = s.z;
    ssrc[p3] = s.w;
  } else if (i < n4 + (E & 3)) {
    int e = 4 * n4 + (i - n4);
    int pos = atomicAdd(&cursor[dst[e]], 1);
    ssrc[pos] = src[e];
  }
}

// ---- Gather 1: mean1[n] = mean of x[neighbors] (64 feats) ----
// 16 lanes x float4 per node, 4 nodes per wave. Per feature, the neighbor
// accumulation order is bit-identical to round 3 (groups of 4, pairwise).
__global__ __launch_bounds__(256) void gather1_kernel(
    const float* __restrict__ x, const int* __restrict__ off,
    const int* __restrict__ ssrc, float* __restrict__ mean1) {
  int t = threadIdx.x;
  int lane = t & 63;
  int sub = lane >> 4;      // which of 4 nodes in this wave
  int l16 = lane & 15;      // float4 index within the 64-feat row
  int node = blockIdx.x * 16 + ((t >> 6) << 2) + sub;
  int srcLane = sub << 4;
  int b = off[node], e = off[node + 1];
  float4 acc = {0.f, 0.f, 0.f, 0.f};
  for (int base = b; base < e; base += 16) {
    int rem = e - base; if (rem > 16) rem = 16;
    int idx = (l16 < rem) ? ssrc[base + l16] : 0;
    int j = 0;
    for (; j + 4 <= rem; j += 4) {
      int s0 = __shfl(idx, srcLane + j, 64);
      int s1 = __shfl(idx, srcLane + j + 1, 64);
      int s2 = __shfl(idx, srcLane + j + 2, 64);
      int s3 = __shfl(idx, srcLane + j + 3, 64);
      float4 v0 = ((const float4*)(x + (size_t)s0 * 64))[l16];
      float4 v1 = ((const float4*)(x + (size_t)s1 * 64))[l16];
      float4 v2 = ((const float4*)(x + (size_t)s2 * 64))[l16];
      float4 v3 = ((const float4*)(x + (size_t)s3 * 64))[l16];
      acc.x += (v0.x + v1.x) + (v2.x + v3.x);
      acc.y += (v0.y + v1.y) + (v2.y + v3.y);
      acc.z += (v0.z + v1.z) + (v2.z + v3.z);
      acc.w += (v0.w + v1.w) + (v2.w + v3.w);
    }
    for (; j < rem; j++) {
      int s = __shfl(idx, srcLane + j, 64);
      float4 v = ((const float4*)(x + (size_t)s * 64))[l16];
      acc.x += v.x; acc.y += v.y; acc.z += v.z; acc.w += v.w;
    }
  }
  float dinv = 1.0f / ((float)(e - b) + EPS);
  float4 o4;
  o4.x = acc.x * dinv; o4.y = acc.y * dinv;
  o4.z = acc.z * dinv; o4.w = acc.w * dinv;
  ((float4*)(mean1 + (size_t)node * 64))[l16] = o4;
}

// ---- Fused MLP: g = relu(mean1 @ W1 + b1) @ W2 ; h1 stays in LDS ----
// Both GEMM loops bit-identical to round 3's mlp1/mlp2a.
__global__ __launch_bounds__(256) void mlp_fused_kernel(
    const float* __restrict__ mean1, const float* __restrict__ W1,
    const float* __restrict__ b1, const float* __restrict__ W2,
    float* __restrict__ g) {
  __shared__ float sW1[64 * 128];   // 32 KB
  __shared__ float sW2[128 * 64];   // 32 KB
  __shared__ float sM[16][64];      // 4 KB
  __shared__ float sH[16][128];     // 8 KB
  int t = threadIdx.x;
  int row0 = blockIdx.x * 16;

  const float4* W1_4 = (const float4*)W1;
  const float4* W2_4 = (const float4*)W2;
  float4* sW1_4 = (float4*)sW1;
  float4* sW2_4 = (float4*)sW2;
#pragma unroll
  for (int i = 0; i < 8; i++) sW1_4[t + 256 * i] = W1_4[t + 256 * i];
#pragma unroll
  for (int i = 0; i < 8; i++) sW2_4[t + 256 * i] = W2_4[t + 256 * i];
  ((float4*)sM)[t] = ((const float4*)(mean1 + (size_t)row0 * 64))[t];
  __syncthreads();

  {  // GEMM1 + relu -> sH
    int c = t & 127;
    int r0 = (t >> 7) * 8;
    float acc[8];
    float bias = b1[c];
#pragma unroll
    for (int r = 0; r < 8; r++) acc[r] = bias;
    for (int k = 0; k < 64; k++) {
      float w = sW1[k * 128 + c];
#pragma unroll
      for (int r = 0; r < 8; r++) acc[r] = fmaf(sM[r0 + r][k], w, acc[r]);
    }
#pragma unroll
    for (int r = 0; r < 8; r++) sH[r0 + r][c] = fmaxf(acc[r], 0.0f);
  }
  __syncthreads();

  {  // GEMM2 -> g
    int c = t & 63;
    int r0 = (t >> 6) * 4;
    float acc[4] = {0.f, 0.f, 0.f, 0.f};
    for (int k = 0; k < 128; k++) {
      float w = sW2[k * 64 + c];
#pragma unroll
      for (int r = 0; r < 4; r++) acc[r] = fmaf(sH[r0 + r][k], w, acc[r]);
    }
#pragma unroll
    for (int r = 0; r < 4; r++)
      g[(size_t)(row0 + r0 + r) * 64 + c] = acc[r];
  }
}

// ---- Gather 2 + bias + log_softmax ----
// Same 16-lane x float4 layout. The softmax reductions reproduce round 3's
// 64-lane butterfly tree exactly: feature f=(l16<<2)|comp; f^32..f^4 are lane
// xors 8,4,2,1; f^2,f^1 are in-lane component pairs (x,z)(y,w) then sum.
__global__ __launch_bounds__(256) void gather2_kernel(
    const float* __restrict__ g, const int* __restrict__ off,
    const int* __restrict__ ssrc, const float* __restrict__ b2,
    float* __restrict__ out) {
  int t = threadIdx.x;
  int lane = t & 63;
  int sub = lane >> 4;
  int l16 = lane & 15;
  int node = blockIdx.x * 16 + ((t >> 6) << 2) + sub;
  int srcLane = sub << 4;
  int b = off[node], e = off[node + 1];
  float4 acc = {0.f, 0.f, 0.f, 0.f};
  for (int base = b; base < e; base += 16) {
    int rem = e - base; if (rem > 16) rem = 16;
    int idx = (l16 < rem) ? ssrc[base + l16] : 0;
    int j = 0;
    for (; j + 4 <= rem; j += 4) {
      int s0 = __shfl(idx, srcLane + j, 64);
      int s1 = __shfl(idx, srcLane + j + 1, 64);
      int s2 = __shfl(idx, srcLane + j + 2, 64);
      int s3 = __shfl(idx, srcLane + j + 3, 64);
      float4 v0 = ((const float4*)(g + (size_t)s0 * 64))[l16];
      float4 v1 = ((const float4*)(g + (size_t)s1 * 64))[l16];
      float4 v2 = ((const float4*)(g + (size_t)s2 * 64))[l16];
      float4 v3 = ((const float4*)(g + (size_t)s3 * 64))[l16];
      acc.x += (v0.x + v1.x) + (v2.x + v3.x);
      acc.y += (v0.y + v1.y) + (v2.y + v3.y);
      acc.z += (v0.z + v1.z) + (v2.z + v3.z);
      acc.w += (v0.w + v1.w) + (v2.w + v3.w);
    }
    for (; j < rem; j++) {
      int s = __shfl(idx, srcLane + j, 64);
      float4 v = ((const float4*)(g + (size_t)s * 64))[l16];
      acc.x += v.x; acc.y += v.y; acc.z += v.z; acc.w += v.w;
    }
  }
  float dinv = 1.0f / ((float)(e - b) + EPS);
  float4 b2v = ((const float4*)b2)[l16];
  float4 val;
  val.x = acc.x * dinv + b2v.x;
  val.y = acc.y * dinv + b2v.y;
  val.z = acc.z * dinv + b2v.z;
  val.w = acc.w * dinv + b2v.w;

  // max: butterfly lane-xors 8,4,2,1 (feature bits 5..2), then comps (bits 1,0)
  float4 m = val;
#pragma unroll
  for (int o = 8; o > 0; o >>= 1) {
    m.x = fmaxf(m.x, __shfl_xor(m.x, o, 64));
    m.y = fmaxf(m.y, __shfl_xor(m.y, o, 64));
    m.z = fmaxf(m.z, __shfl_xor(m.z, o, 64));
    m.w = fmaxf(m.w, __shfl_xor(m.w, o, 64));
  }
  float mx = fmaxf(fmaxf(m.x, m.z), fmaxf(m.y, m.w));

  // sum of exp: same tree as round 3's 64-lane butterfly (o=32..1 on f)
  float4 ex;
  ex.x = __expf(val.x - mx);
  ex.y = __expf(val.y - mx);
  ex.z = __expf(val.z - mx);
  ex.w = __expf(val.w - mx);
#pragma unroll
  for (int o = 8; o > 0; o >>= 1) {
    ex.x += __shfl_xor(ex.x, o, 64);
    ex.y += __shfl_xor(ex.y, o, 64);
    ex.z += __shfl_xor(ex.z, o, 64);
    ex.w += __shfl_xor(ex.w, o, 64);
  }
  float sm = (ex.x + ex.z) + (ex.y + ex.w);

  float ls = logf(sm);
  float4 o4;
  o4.x = (val.x - mx) - ls;
  o4.y = (val.y - mx) - ls;
  o4.z = (val.z - mx) - ls;
  o4.w = (val.w - mx) - ls;
  ((float4*)(out + (size_t)node * 64))[l16] = o4;
}

extern "C" void kernel_launch(void* const* d_in, const int* in_sizes, int n_in,
                              void* d_out, int out_size, void* d_ws, size_t ws_size,
                              hipStream_t stream) {
  const float* x   = (const float*)d_in[0];
  const int*   src = (const int*)d_in[1];
  const int*   dst = (const int*)d_in[2];
  const float* W1  = (const float*)d_in[3];
  const float* b1  = (const float*)d_in[4];
  const float* W2  = (const float*)d_in[5];
  const float* b2  = (const float*)d_in[6];
  float* out = (float*)d_out;
  int E = in_sizes[1];

  const int PAD = 50176;  // SCAN_BLOCKS*256
  int* cnt    = (int*)d_ws;
  int* off    = cnt + PAD;
  int* cursor = off + PAD;
  int* bsum   = cursor + PAD;           // 256 ints
  int* ssrc   = bsum + 256;
  float* mean1 = (float*)(ssrc + 800000);
  float* g     = mean1 + (size_t)N_NODES * 64;

  int ntot = (E >> 2) + (E & 3);
  hipMemsetAsync(cnt, 0, (size_t)N_NODES * sizeof(int), stream);
  hist_kernel<<<(ntot + 255) / 256, 256, 0, stream>>>(dst, cnt, E);
  scan1_kernel<<<SCAN_BLOCKS, 256, 0, stream>>>(cnt, bsum);
  scan2_kernel<<<1, 256, 0, stream>>>(bsum, off);
  scan3_kernel<<<SCAN_BLOCKS, 256, 0, stream>>>(cnt, bsum, off, cursor);
  fill_kernel<<<(ntot + 255) / 256, 256, 0, stream>>>(src, dst, cursor, ssrc, E);

  gather1_kernel<<<N_NODES / 16, 256, 0, stream>>>(x, off, ssrc, mean1);       // 3125 blocks
  mlp_fused_kernel<<<N_NODES / 16, 256, 0, stream>>>(mean1, W1, b1, W2, g);
  gather2_kernel<<<N_NODES / 16, 256, 0, stream>>>(g, off, ssrc, b2, out);
}